// Round 1
// baseline (11.094 us; speedup 1.0000x reference)
//
#include <hip/hip_runtime.h>

// Quanvolution, n_layers == 1, analytic form.
//
// Per 2x2 patch (phi0=p00, phi1=p01, phi2=p10, phi3=p11):
//   c_k = cos(pi*phi_k + theta_k)
//   ev0 = c1*c2*c3
//   ev1 = c0*c1
//   ev2 = c0*c1*c2
//   ev3 = c0*c1*c2*c3
// Derivation: RY(pi*phi)RY(theta) merge -> product state; CNOT ring conjugates
// Z_q into products of Z's; <Z_k> of a product state = cos(full angle).

__global__ __launch_bounds__(256) void quanv_ev_kernel(
    const float* __restrict__ x, const float* __restrict__ rp,
    float* __restrict__ out)
{
    constexpr int W = 2048;         // input width
    // OW = 1024 output cols; each thread does 2 adjacent patches -> 512 thread-cols
    const float inv2pi = 0.15915494309189535f;
    // uniform per-launch: theta_q / (2*pi)  (v_cos takes revolutions)
    float t0 = rp[0] * inv2pi;
    float t1 = rp[1] * inv2pi;
    float t2 = rp[2] * inv2pi;
    float t3 = rp[3] * inv2pi;

    int t   = blockIdx.x * 256 + threadIdx.x;   // 0 .. 1024*512-1
    int oi  = t >> 9;            // output row (patch row)
    int oj2 = (t & 511) << 1;    // first patch col (even)

    // two input rows of the 2x2 patches; float4 = 2 patches horizontally
    const float4 r0 = *reinterpret_cast<const float4*>(x + (size_t)(2 * oi)     * W + 2 * oj2);
    const float4 r1 = *reinterpret_cast<const float4*>(x + (size_t)(2 * oi + 1) * W + 2 * oj2);

    // revolutions = phi*0.5 + theta/(2pi), in [0, 1.5) -> v_cos accurate, no fract
    float c0a = __builtin_amdgcn_cosf(fmaf(r0.x, 0.5f, t0));
    float c1a = __builtin_amdgcn_cosf(fmaf(r0.y, 0.5f, t1));
    float c2a = __builtin_amdgcn_cosf(fmaf(r1.x, 0.5f, t2));
    float c3a = __builtin_amdgcn_cosf(fmaf(r1.y, 0.5f, t3));

    float c0b = __builtin_amdgcn_cosf(fmaf(r0.z, 0.5f, t0));
    float c1b = __builtin_amdgcn_cosf(fmaf(r0.w, 0.5f, t1));
    float c2b = __builtin_amdgcn_cosf(fmaf(r1.z, 0.5f, t2));
    float c3b = __builtin_amdgcn_cosf(fmaf(r1.w, 0.5f, t3));

    float4 oA, oB;
    float e1a = c0a * c1a, c23a = c2a * c3a;
    oA.x = c1a * c23a;      // ev0
    oA.y = e1a;             // ev1
    oA.z = e1a * c2a;       // ev2
    oA.w = e1a * c23a;      // ev3

    float e1b = c0b * c1b, c23b = c2b * c3b;
    oB.x = c1b * c23b;
    oB.y = e1b;
    oB.z = e1b * c2b;
    oB.w = e1b * c23b;

    // patch A index p = oi*1024 + oj2 ; out offset = 4*p = 8*t
    float4* o = reinterpret_cast<float4*>(out + (size_t)t * 8);
    o[0] = oA;
    o[1] = oB;
}

extern "C" void kernel_launch(void* const* d_in, const int* in_sizes, int n_in,
                              void* d_out, int out_size, void* d_ws, size_t ws_size,
                              hipStream_t stream) {
    const float* x  = (const float*)d_in[0];
    const float* rp = (const float*)d_in[1];
    float* out = (float*)d_out;

    // 1024 x 1024 patches, 2 patches per thread -> 524288 threads
    const int threads = 1024 * 512;
    quanv_ev_kernel<<<threads / 256, 256, 0, stream>>>(x, rp, out);
}

// Round 3
// 11.011 us; speedup vs baseline: 1.0076x; 1.0076x over previous
//
#include <hip/hip_runtime.h>

// Quanvolution, n_layers == 1, analytic form.
//
// Per 2x2 patch (phi0=p00, phi1=p01, phi2=p10, phi3=p11):
//   c_k = cos(pi*phi_k + theta_k)
//   ev0 = c1*c2*c3 ; ev1 = c0*c1 ; ev2 = c0*c1*c2 ; ev3 = c0*c1*c2*c3
// Derivation: RY(pi*phi)RY(theta) merge -> product state; CNOT ring conjugates
// Z_q into products of Z's; <Z> of a product state = cos(full angle).
//
// Each work item = 2 horizontally adjacent patches (2x float4 in, 2x float4 out).
// UNROLL=4 work items per thread, all 8 loads issued before use (MLP/ILP).

typedef float f32x4 __attribute__((ext_vector_type(4)));

constexpr int W = 2048;
constexpr int TOTAL_ITEMS = 1024 * 512;        // 2-patch work items
constexpr int UNROLL = 4;
constexpr int THREADS = TOTAL_ITEMS / UNROLL;  // 131072
constexpr int BLOCK = 256;

__global__ __launch_bounds__(BLOCK) void quanv_ev_kernel(
    const float* __restrict__ x, const float* __restrict__ rp,
    float* __restrict__ out)
{
    const float inv2pi = 0.15915494309189535f;
    float t0 = rp[0] * inv2pi;
    float t1 = rp[1] * inv2pi;
    float t2 = rp[2] * inv2pi;
    float t3 = rp[3] * inv2pi;

    int tid = blockIdx.x * BLOCK + threadIdx.x;

    f32x4 r0[UNROLL], r1[UNROLL];
#pragma unroll
    for (int k = 0; k < UNROLL; ++k) {
        int w = tid + k * THREADS;
        int oi = w >> 9;              // patch row
        int oj2 = (w & 511) << 1;     // first patch col (even)
        const float* base = x + (size_t)(2 * oi) * W + 2 * oj2;
        r0[k] = *reinterpret_cast<const f32x4*>(base);
        r1[k] = *reinterpret_cast<const f32x4*>(base + W);
    }

#pragma unroll
    for (int k = 0; k < UNROLL; ++k) {
        int w = tid + k * THREADS;

        float c0a = __builtin_amdgcn_cosf(fmaf(r0[k].x, 0.5f, t0));
        float c1a = __builtin_amdgcn_cosf(fmaf(r0[k].y, 0.5f, t1));
        float c2a = __builtin_amdgcn_cosf(fmaf(r1[k].x, 0.5f, t2));
        float c3a = __builtin_amdgcn_cosf(fmaf(r1[k].y, 0.5f, t3));

        float c0b = __builtin_amdgcn_cosf(fmaf(r0[k].z, 0.5f, t0));
        float c1b = __builtin_amdgcn_cosf(fmaf(r0[k].w, 0.5f, t1));
        float c2b = __builtin_amdgcn_cosf(fmaf(r1[k].z, 0.5f, t2));
        float c3b = __builtin_amdgcn_cosf(fmaf(r1[k].w, 0.5f, t3));

        f32x4 oA, oB;
        float e1a = c0a * c1a, c23a = c2a * c3a;
        oA.x = c1a * c23a;
        oA.y = e1a;
        oA.z = e1a * c2a;
        oA.w = e1a * c23a;

        float e1b = c0b * c1b, c23b = c2b * c3b;
        oB.x = c1b * c23b;
        oB.y = e1b;
        oB.z = e1b * c2b;
        oB.w = e1b * c23b;

        f32x4* o = reinterpret_cast<f32x4*>(out + (size_t)w * 8);
        __builtin_nontemporal_store(oA, o);
        __builtin_nontemporal_store(oB, o + 1);
    }
}

extern "C" void kernel_launch(void* const* d_in, const int* in_sizes, int n_in,
                              void* d_out, int out_size, void* d_ws, size_t ws_size,
                              hipStream_t stream) {
    const float* x  = (const float*)d_in[0];
    const float* rp = (const float*)d_in[1];
    float* out = (float*)d_out;

    quanv_ev_kernel<<<THREADS / BLOCK, BLOCK, 0, stream>>>(x, rp, out);
}